// Round 12
// baseline (417.081 us; speedup 1.0000x reference)
//
#include <hip/hip_runtime.h>
#include <float.h>

#define NN 50000
#define NE 800000
#define NG 64
#define CAP 64
#define EPT 16   // edges per thread in k_count

typedef __attribute__((ext_vector_type(8))) _Float16 f16x8;
typedef __attribute__((ext_vector_type(4))) float f32x4;
typedef __attribute__((ext_vector_type(4))) _Float16 half4;
typedef unsigned int u32;
typedef unsigned short u16;

// ---------- helpers ----------
__device__ __forceinline__ unsigned f2mono(float f) {
  unsigned b = __float_as_uint(f);
  return (b & 0x80000000u) ? ~b : (b | 0x80000000u);
}
__device__ __forceinline__ float mono2f(unsigned u) {
  unsigned b = (u & 0x80000000u) ? (u & 0x7fffffffu) : ~u;
  return __uint_as_float(b);
}
// async global->LDS 16B DMA (gfx950). LDS dest must be wave-uniform base + lane*16.
// NOTE (r2/r3/r11): leaving these DMAs in flight ACROSS an MFMA phase (drain at the
// NEXT barrier) wedged the container 3/3 times on this harness. Only issue->drain->use.
__device__ __forceinline__ void gl_lds16(const void* g, void* l) {
  __builtin_amdgcn_global_load_lds((const __attribute__((address_space(1))) u32*)g,
                                   (__attribute__((address_space(3))) u32*)l, 16, 0, 0);
}

// ---------- degree count + ELL fill, XCD-partitioned (r6 proven: 44->~10MB wr) ----------
__global__ __launch_bounds__(256) void k_count(const int* __restrict__ src,
                                               const int* __restrict__ dst,
                                               int* __restrict__ cnt,
                                               u16* __restrict__ col) {
  int s = blockIdx.x & 7;
  int base = (blockIdx.x >> 3) * (256 * EPT) + threadIdx.x;
#pragma unroll
  for (int r = 0; r < EPT; ++r) {
    int e = base + r * 256;
    if (e >= NE) break;
    int d = dst[e];
    if ((d & 7) != s) continue;
    if ((unsigned)d >= NN) continue;
    int sv = src[e];
    if ((unsigned)sv >= NN) continue;
    int pos = atomicAdd(&cnt[d], 1);
    if (pos < CAP) col[d * CAP + pos] = (u16)sv;
  }
}

// dinv + pre-scaled input features xs = x * dinv[v]; also zero-init pool buffer
__global__ void k_dinv(const int* __restrict__ cnt, float* __restrict__ dinv,
                       const float* __restrict__ x, float* __restrict__ xs,
                       unsigned* __restrict__ g) {
  int v = blockIdx.x * blockDim.x + threadIdx.x;
  if (v >= NN) return;
  if (v < NG * 256) g[v] = 0u;
  float d = rsqrtf((float)cnt[v] + 1.0f);
  dinv[v] = d;
#pragma unroll
  for (int i = 0; i < 9; ++i) xs[v * 9 + i] = x[v * 9 + i] * d;
}

// ---------- fused weight split+transpose for W2,W3,W4: W[K][Nc] -> Wh/Wl[Nc][K] ----------
__device__ __forceinline__ void splitw1(const float* W, _Float16* Wh, _Float16* Wl,
                                        int i, int K, int Nc) {
  int k = i / Nc, n = i - k * Nc;
  float w = W[i];
  _Float16 h = (_Float16)w;
  _Float16 l = (_Float16)(w - (float)h);
  Wh[(size_t)n * K + k] = h;
  Wl[(size_t)n * K + k] = l;
}
__global__ void k_splitw3(const float* __restrict__ W2, const float* __restrict__ W3,
                          const float* __restrict__ W4,
                          _Float16* __restrict__ W2h, _Float16* __restrict__ W2l,
                          _Float16* __restrict__ W3h, _Float16* __restrict__ W3l,
                          _Float16* __restrict__ W4h, _Float16* __restrict__ W4l) {
  int i = blockIdx.x * 256 + threadIdx.x;
  const int n2 = 128 * 256, n3 = 256 * 256;
  if (i < n2) splitw1(W2, W2h, W2l, i, 128, 256);
  else if (i < n2 + n3) splitw1(W3, W3h, W3l, i - n2, 256, 256);
  else if (i < n2 + 2 * n3) splitw1(W4, W4h, W4l, i - n2 - n3, 256, 256);
}

// ---------- FUSED layer 1: agg9 gather + GEMM 9->128 (+bias, relu, *dinv) ----------
// 3125 blocks x 256 thr; 16 nodes/block (50000 = 16*3125 exactly -> uniform barriers).
__global__ __launch_bounds__(256) void k_l1(const float* __restrict__ xs,
                                            const float* __restrict__ W,
                                            const float* __restrict__ bias,
                                            const float* __restrict__ dinv,
                                            const int* __restrict__ cnt,
                                            const u16* __restrict__ col,
                                            _Float16* __restrict__ out) {
  __shared__ float sW[9 * 128];
  __shared__ float sb[128];
  __shared__ float sX[16][12];      // 9 used, padded
  int t = threadIdx.x;
  if (t < 128) sb[t] = bias[t];
  for (int i = t; i < 9 * 128; i += 256) sW[i] = W[i];
  // gather phase
  int g = t >> 4, l = t & 15;
  int v = blockIdx.x * 16 + g;      // always < NN (exact tiling)
  int c = cnt[v]; if (c > CAP) c = CAP;
  const u16* cl = col + (size_t)v * CAP;
  float acc = (l < 9) ? xs[v * 9 + l] : 0.0f;
  int j = 0;
  for (; j + 4 <= c; j += 4) {
    ushort4 u = *(const ushort4*)(cl + j);
    float a0 = (l < 9) ? xs[(int)u.x * 9 + l] : 0.f;
    float a1 = (l < 9) ? xs[(int)u.y * 9 + l] : 0.f;
    float a2 = (l < 9) ? xs[(int)u.z * 9 + l] : 0.f;
    float a3 = (l < 9) ? xs[(int)u.w * 9 + l] : 0.f;
    acc += (a0 + a1) + (a2 + a3);
  }
  for (; j < c; ++j) {
    int u = cl[j];
    if (l < 9) acc += xs[u * 9 + l];
  }
  if (l < 9) sX[g][l] = acc * dinv[v];
  __syncthreads();
  // gemm phase
  int cc = t & 127;
  int g0 = (t >> 7) * 8;
#pragma unroll
  for (int rr = 0; rr < 8; ++rr) {
    int gi = g0 + rr;
    int r = blockIdx.x * 16 + gi;
    float a = sb[cc];
#pragma unroll
    for (int i = 0; i < 9; ++i) a += sX[gi][i] * sW[i * 128 + cc];
    out[(size_t)r * 128 + cc] = (_Float16)(fmaxf(a, 0.0f) * dinv[r]);
  }
}

// ---------- XCD-sliced aggregation, 4-deep (r6 proven best: 58.0 us @F=256) ----------
// F=256 gather pinned ~58 us across 4 structural variants -> fabric floor; lane closed.
// chunk0: node-range offset so a dispatch can cover a half-range (instrumentation:
// splitting aggs256 into two ~29us dispatches drops the top-5 cutoff so k_mm's
// counters become visible next round). Slice decode (bid & mask) unchanged.
__global__ __launch_bounds__(256) void k_aggs(const half4* __restrict__ h,
                                              half4* __restrict__ out,
                                              const int* __restrict__ cnt,
                                              const u16* __restrict__ col,
                                              const float* __restrict__ dinv,
                                              int rowU, int slog, int chunk0) {
  int bid = blockIdx.x;
  int s = bid & ((1 << slog) - 1);
  int chunk = chunk0 + (bid >> slog);
  int g = threadIdx.x >> 4;
  int l = threadIdx.x & 15;
  int v = chunk * 16 + g;
  if (v >= NN) return;
  int so = s * 16 + l;                 // half4 offset within row
  int c = cnt[v]; if (c > CAP) c = CAP;
  const u16* cl = col + (size_t)v * CAP;
  half4 sv = h[(size_t)v * rowU + so];
  float ax = (float)sv.x, ay = (float)sv.y, az = (float)sv.z, aw = (float)sv.w;
  int j = 0;
  for (; j + 4 <= c; j += 4) {
    ushort4 u = *(const ushort4*)(cl + j);
    half4 t0 = h[(size_t)u.x * rowU + so];
    half4 t1 = h[(size_t)u.y * rowU + so];
    half4 t2 = h[(size_t)u.z * rowU + so];
    half4 t3 = h[(size_t)u.w * rowU + so];
    ax += ((float)t0.x + (float)t1.x) + ((float)t2.x + (float)t3.x);
    ay += ((float)t0.y + (float)t1.y) + ((float)t2.y + (float)t3.y);
    az += ((float)t0.z + (float)t1.z) + ((float)t2.z + (float)t3.z);
    aw += ((float)t0.w + (float)t1.w) + ((float)t2.w + (float)t3.w);
  }
  for (; j < c; ++j) {
    half4 tv = h[(size_t)cl[j] * rowU + so];
    ax += (float)tv.x; ay += (float)tv.y; az += (float)tv.z; aw += (float)tv.w;
  }
  float d = dinv[v];
  half4 o;
  o.x = (_Float16)(ax * d); o.y = (_Float16)(ay * d);
  o.z = (_Float16)(az * d); o.w = (_Float16)(aw * d);
  out[(size_t)v * rowU + so] = o;
}

// ---------- MFMA fp16 hi/lo-weight GEMM, DMA LDS staging (r9 proven form, 404.3us) ----------
// 1D grid 784, XCD-aware decode: the two col-blocks of the same 128 rows get
// blockIdx differing by exactly 8 -> same XCD under %8 round-robin -> A-tile
// L2 reuse. r = (b>>4)*8 + (b&7), c = (b>>3)&1.
__global__ __launch_bounds__(256) void k_mm(const _Float16* __restrict__ A,
                                            const _Float16* __restrict__ Bh,
                                            const _Float16* __restrict__ Bl,
                                            const float* __restrict__ bias,
                                            _Float16* __restrict__ C,
                                            const float* __restrict__ dinv,
                                            const int* __restrict__ batch,
                                            unsigned* __restrict__ gpool,
                                            int M, int K, int Nc, int mode) {
  __shared__ __align__(16) _Float16 Alds[128 * 64];   // 16 KB
  __shared__ __align__(16) _Float16 Bhl[128 * 64];    // 16 KB
  __shared__ __align__(16) _Float16 Bll[128 * 64];    // 16 KB
  int bid = blockIdx.x;
  int rblk = (bid >> 4) * 8 + (bid & 7);
  int cblk = (bid >> 3) & 1;
  if (rblk * 128 >= M) return;
  int rowBase = rblk * 128;
  int colBase = cblk * 128;
  int t = threadIdx.x;
  int wave = t >> 6, lane = t & 63;
  int wm = wave & 1, wn = wave >> 1;
  int lm = lane & 15;
  int q  = lane >> 4;

  int srl = wave * 32 + (lane >> 3);
  int sj  = lane & 7;
  int ssw = lane >> 3;
  int gseg = sj ^ ssw;

  f32x4 acc[4][4];
#pragma unroll
  for (int i = 0; i < 4; ++i)
#pragma unroll
    for (int j = 0; j < 4; ++j) acc[i][j] = (f32x4){0.f, 0.f, 0.f, 0.f};

  int nit = K >> 6;
  for (int it = 0; it < nit; ++it) {
    __syncthreads();
#pragma unroll
    for (int c = 0; c < 4; ++c) {
      int rl = srl + c * 8;
      int ga = rowBase + rl; if (ga > M - 1) ga = M - 1;
      int gb = colBase + rl;
      unsigned off = (unsigned)it * 64 + gseg * 8;
      int ldst = (wave * 32 + c * 8) * 64 + lane * 8;
      gl_lds16(A  + (size_t)ga * K + off, Alds + ldst);
      gl_lds16(Bh + (size_t)gb * K + off, Bhl + ldst);
      gl_lds16(Bl + (size_t)gb * K + off, Bll + ldst);
    }
    __syncthreads();

#pragma unroll
    for (int s2 = 0; s2 < 2; ++s2) {
      int slotq = ((s2 << 2) | q);
      f16x8 vbh[4], vbl[4];
#pragma unroll
      for (int ni = 0; ni < 4; ++ni) {
        int rB = wn * 64 + ni * 16 + lm;
        int slot = slotq ^ (lm & 7);
        vbh[ni] = *(const f16x8*)(Bhl + rB * 64 + slot * 8);
        vbl[ni] = *(const f16x8*)(Bll + rB * 64 + slot * 8);
      }
#pragma unroll
      for (int mi = 0; mi < 4; ++mi) {
        int rA = wm * 64 + mi * 16 + lm;
        int slot = slotq ^ (lm & 7);
        f16x8 va = *(const f16x8*)(Alds + rA * 64 + slot * 8);
#pragma unroll
        for (int ni = 0; ni < 4; ++ni) {
          acc[mi][ni] = __builtin_amdgcn_mfma_f32_16x16x32_f16(va, vbh[ni], acc[mi][ni], 0, 0, 0);
          acc[mi][ni] = __builtin_amdgcn_mfma_f32_16x16x32_f16(va, vbl[ni], acc[mi][ni], 0, 0, 0);
        }
      }
    }
  }

  int rowOff = (lane >> 4) * 4;
  if (mode == 2) {
    __syncthreads();
    unsigned* ldsPool = (unsigned*)Alds;
    for (int i = t; i < 4 * 256; i += 256) ldsPool[i] = 0u;
    __syncthreads();
    int b0 = batch[rowBase];
#pragma unroll
    for (int mi = 0; mi < 4; ++mi) {
#pragma unroll
      for (int ni = 0; ni < 4; ++ni) {
        int gc = colBase + wn * 64 + ni * 16 + lm;
        float bsv = bias[gc];
#pragma unroll
        for (int r = 0; r < 4; ++r) {
          int gr = rowBase + wm * 64 + mi * 16 + rowOff + r;
          if (gr < M) {
            float v = acc[mi][ni][r] + bsv;
            int idx = batch[gr] - b0;
            if (idx < 0) idx = 0;
            if (idx > 3) idx = 3;
            atomicMax(&ldsPool[idx * 256 + gc], f2mono(v));
          }
        }
      }
    }
    __syncthreads();
#pragma unroll
    for (int s4 = 0; s4 < 4; ++s4) {
      unsigned mv = ldsPool[s4 * 256 + t];
      int gb = b0 + s4;
      if (mv && gb < NG) atomicMax(&gpool[gb * 256 + t], mv);
    }
  } else {
#pragma unroll
    for (int mi = 0; mi < 4; ++mi) {
#pragma unroll
      for (int ni = 0; ni < 4; ++ni) {
        int gc = colBase + wn * 64 + ni * 16 + lm;
        float bsv = bias[gc];
#pragma unroll
        for (int r = 0; r < 4; ++r) {
          int gr = rowBase + wm * 64 + mi * 16 + rowOff + r;
          if (gr < M) {
            float v = fmaxf(acc[mi][ni][r] + bsv, 0.0f);
            C[(size_t)gr * Nc + gc] = (_Float16)(v * dinv[gr]);
          }
        }
      }
    }
  }
}

// ---------- dense head ----------
__global__ __launch_bounds__(256) void k_head(const unsigned* __restrict__ g,
                                              const float* __restrict__ Wl2, const float* __restrict__ bl2,
                                              const float* __restrict__ Wl3, const float* __restrict__ bl3,
                                              const float* __restrict__ Wl, const float* __restrict__ bl,
                                              float* __restrict__ out) {
  __shared__ float s0[256];
  __shared__ float s1[128];
  __shared__ float s2[128];
  int b = blockIdx.x, t = threadIdx.x;
  s0[t] = mono2f(g[b * 256 + t]);
  __syncthreads();
  if (t < 128) {
    float acc = bl2[t];
    for (int k = 0; k < 256; ++k) acc += s0[k] * Wl2[k * 128 + t];
    s1[t] = fmaxf(acc, 0.0f);
  }
  __syncthreads();
  if (t < 128) {
    float acc = bl3[t];
    for (int k = 0; k < 128; ++k) acc += s1[k] * Wl3[k * 128 + t];
    s2[t] = fmaxf(acc, 0.0f);
  }
  __syncthreads();
  if (t < 10) {
    float acc = bl[t];
    for (int k = 0; k < 128; ++k) acc += s2[k] * Wl[k * 10 + t];
    out[b * 10 + t] = acc;
  }
}

extern "C" void kernel_launch(void* const* d_in, const int* in_sizes, int n_in,
                              void* d_out, int out_size, void* d_ws, size_t ws_size,
                              hipStream_t stream) {
  const float* x   = (const float*)d_in[0];
  const int* eidx  = (const int*)d_in[1];
  const int* batch = (const int*)d_in[2];
  const float* W1 = (const float*)d_in[3];   const float* b1 = (const float*)d_in[4];
  const float* W2 = (const float*)d_in[5];   const float* b2 = (const float*)d_in[6];
  const float* W3 = (const float*)d_in[7];   const float* b3 = (const float*)d_in[8];
  const float* W4 = (const float*)d_in[9];   const float* b4 = (const float*)d_in[10];
  const float* Wl2 = (const float*)d_in[11]; const float* bl2 = (const float*)d_in[12];
  const float* Wl3 = (const float*)d_in[13]; const float* bl3 = (const float*)d_in[14];
  const float* Wl  = (const float*)d_in[15]; const float* bl  = (const float*)d_in[16];
  float* out = (float*)d_out;

  // ---- workspace carve ----
  _Float16* bufA = (_Float16*)d_ws;                                // NN*256 fp16
  _Float16* bufB = bufA + (size_t)NN * 256;                        // NN*256 fp16
  int* cnt  = (int*)(bufB + (size_t)NN * 256);                     // NN
  float* dinv = (float*)(cnt + NN);                                // NN
  u16* col  = (u16*)(dinv + NN);                                   // NN*CAP ushort
  unsigned* g = (unsigned*)(col + (size_t)NN * CAP);               // NG*256
  _Float16* W2h = (_Float16*)(g + NG * 256);                       // 256*128
  _Float16* W2l = W2h + 256 * 128;
  _Float16* W3h = W2l + 256 * 128;                                 // 256*256
  _Float16* W3l = W3h + 256 * 256;
  _Float16* W4h = W3l + 256 * 256;
  _Float16* W4l = W4h + 256 * 256;
  float* xs = (float*)bufB;        // NN*9 fp32 in bufB: dead before layer-2 aggs writes bufB

  const int* src = eidx;
  const int* dst = eidx + NE;

  hipMemsetAsync(cnt, 0, NN * sizeof(int), stream);

  const int cntGrid = 8 * ((NE + 256 * EPT - 1) / (256 * EPT));
  k_count<<<cntGrid, 256, 0, stream>>>(src, dst, cnt, col);
  k_dinv<<<(NN + 255) / 256, 256, 0, stream>>>(cnt, dinv, x, xs, g);

  k_splitw3<<<(128 * 256 + 2 * 256 * 256 + 255) / 256, 256, 0, stream>>>(
      W2, W3, W4, W2h, W2l, W3h, W3l, W4h, W4l);

  const int nchunk = (NN + 15) / 16;           // 3125: 16 nodes per block, exact
  const int hcA = 1563, hcB = 1562;            // 1563 + 1562 = 3125 (half-range split)
  const int mmGrid = 784;                      // 392 row-blocks x 2 col-blocks, XCD-paired

  // layer 1: FUSED agg9 + GEMM 9->128 (+relu, *dinv) xs(bufB) -> bufA fp16
  k_l1<<<nchunk, 256, 0, stream>>>(xs, W1, b1, dinv, cnt, col, bufA);

  // layer 2: sliced gather 128-dim bufA->bufB (2 slices), MFMA GEMM 128->256 bufB->bufA
  k_aggs<<<nchunk * 2, 256, 0, stream>>>((const half4*)bufA, (half4*)bufB, cnt, col, dinv, 32, 1, 0);
  k_mm<<<mmGrid, 256, 0, stream>>>(bufB, W2h, W2l, b2, bufA, dinv, batch, g, NN, 128, 256, 1);

  // layer 3: sliced gather 256-dim bufA->bufB (4 slices, 2 half-range dispatches), GEMM bufB->bufA
  k_aggs<<<hcA * 4, 256, 0, stream>>>((const half4*)bufA, (half4*)bufB, cnt, col, dinv, 64, 2, 0);
  k_aggs<<<hcB * 4, 256, 0, stream>>>((const half4*)bufA, (half4*)bufB, cnt, col, dinv, 64, 2, hcA);
  k_mm<<<mmGrid, 256, 0, stream>>>(bufB, W3h, W3l, b3, bufA, dinv, batch, g, NN, 256, 256, 1);

  // layer 4: sliced gather 256-dim bufA->bufB (2 half-range dispatches), GEMM + max-pool
  k_aggs<<<hcA * 4, 256, 0, stream>>>((const half4*)bufA, (half4*)bufB, cnt, col, dinv, 64, 2, 0);
  k_aggs<<<hcB * 4, 256, 0, stream>>>((const half4*)bufA, (half4*)bufB, cnt, col, dinv, 64, 2, hcA);
  k_mm<<<mmGrid, 256, 0, stream>>>(bufB, W4h, W4l, b4, bufA, dinv, batch, g, NN, 256, 256, 2);

  // head
  k_head<<<NG, 256, 0, stream>>>(g, Wl2, bl2, Wl3, bl3, Wl, bl, out);
}

// Round 13
// 414.517 us; speedup vs baseline: 1.0062x; 1.0062x over previous
//
#include <hip/hip_runtime.h>
#include <float.h>

#define NN 50000
#define NE 800000
#define NG 64
#define CAP 64
#define EPT 16   // edges per thread in k_count

typedef __attribute__((ext_vector_type(8))) _Float16 f16x8;
typedef __attribute__((ext_vector_type(4))) float f32x4;
typedef __attribute__((ext_vector_type(4))) _Float16 half4;
typedef unsigned int u32;
typedef unsigned short u16;

// ---------- helpers ----------
__device__ __forceinline__ unsigned f2mono(float f) {
  unsigned b = __float_as_uint(f);
  return (b & 0x80000000u) ? ~b : (b | 0x80000000u);
}
__device__ __forceinline__ float mono2f(unsigned u) {
  unsigned b = (u & 0x80000000u) ? (u & 0x7fffffffu) : ~u;
  return __uint_as_float(b);
}
// async global->LDS 16B DMA (gfx950). LDS dest must be wave-uniform base + lane*16.
// NOTE (r2/r3/r11): leaving these DMAs in flight ACROSS an MFMA phase wedged the
// container 3/3 times. Only issue->drain->use. Cross-phase overlap must use
// normal global_load -> reg -> ds_write (T14), which is safe.
__device__ __forceinline__ void gl_lds16(const void* g, void* l) {
  __builtin_amdgcn_global_load_lds((const __attribute__((address_space(1))) u32*)g,
                                   (__attribute__((address_space(3))) u32*)l, 16, 0, 0);
}

// ---------- degree count + ELL fill, XCD-partitioned (r6 proven: 44->~10MB wr) ----------
__global__ __launch_bounds__(256) void k_count(const int* __restrict__ src,
                                               const int* __restrict__ dst,
                                               int* __restrict__ cnt,
                                               u16* __restrict__ col) {
  int s = blockIdx.x & 7;
  int base = (blockIdx.x >> 3) * (256 * EPT) + threadIdx.x;
#pragma unroll
  for (int r = 0; r < EPT; ++r) {
    int e = base + r * 256;
    if (e >= NE) break;
    int d = dst[e];
    if ((d & 7) != s) continue;
    if ((unsigned)d >= NN) continue;
    int sv = src[e];
    if ((unsigned)sv >= NN) continue;
    int pos = atomicAdd(&cnt[d], 1);
    if (pos < CAP) col[d * CAP + pos] = (u16)sv;
  }
}

// dinv + pre-scaled input features xs = x * dinv[v]; also zero-init pool buffer
__global__ void k_dinv(const int* __restrict__ cnt, float* __restrict__ dinv,
                       const float* __restrict__ x, float* __restrict__ xs,
                       unsigned* __restrict__ g) {
  int v = blockIdx.x * blockDim.x + threadIdx.x;
  if (v >= NN) return;
  if (v < NG * 256) g[v] = 0u;
  float d = rsqrtf((float)cnt[v] + 1.0f);
  dinv[v] = d;
#pragma unroll
  for (int i = 0; i < 9; ++i) xs[v * 9 + i] = x[v * 9 + i] * d;
}

// ---------- fused weight split+transpose for W2,W3,W4: W[K][Nc] -> Wh/Wl[Nc][K] ----------
__device__ __forceinline__ void splitw1(const float* W, _Float16* Wh, _Float16* Wl,
                                        int i, int K, int Nc) {
  int k = i / Nc, n = i - k * Nc;
  float w = W[i];
  _Float16 h = (_Float16)w;
  _Float16 l = (_Float16)(w - (float)h);
  Wh[(size_t)n * K + k] = h;
  Wl[(size_t)n * K + k] = l;
}
__global__ void k_splitw3(const float* __restrict__ W2, const float* __restrict__ W3,
                          const float* __restrict__ W4,
                          _Float16* __restrict__ W2h, _Float16* __restrict__ W2l,
                          _Float16* __restrict__ W3h, _Float16* __restrict__ W3l,
                          _Float16* __restrict__ W4h, _Float16* __restrict__ W4l) {
  int i = blockIdx.x * 256 + threadIdx.x;
  const int n2 = 128 * 256, n3 = 256 * 256;
  if (i < n2) splitw1(W2, W2h, W2l, i, 128, 256);
  else if (i < n2 + n3) splitw1(W3, W3h, W3l, i - n2, 256, 256);
  else if (i < n2 + 2 * n3) splitw1(W4, W4h, W4l, i - n2 - n3, 256, 256);
}

// ---------- FUSED layer 1: agg9 gather + GEMM 9->128 (+bias, relu, *dinv) ----------
// 3125 blocks x 256 thr; 16 nodes/block (50000 = 16*3125 exactly -> uniform barriers).
__global__ __launch_bounds__(256) void k_l1(const float* __restrict__ xs,
                                            const float* __restrict__ W,
                                            const float* __restrict__ bias,
                                            const float* __restrict__ dinv,
                                            const int* __restrict__ cnt,
                                            const u16* __restrict__ col,
                                            _Float16* __restrict__ out) {
  __shared__ float sW[9 * 128];
  __shared__ float sb[128];
  __shared__ float sX[16][12];      // 9 used, padded
  int t = threadIdx.x;
  if (t < 128) sb[t] = bias[t];
  for (int i = t; i < 9 * 128; i += 256) sW[i] = W[i];
  // gather phase
  int g = t >> 4, l = t & 15;
  int v = blockIdx.x * 16 + g;      // always < NN (exact tiling)
  int c = cnt[v]; if (c > CAP) c = CAP;
  const u16* cl = col + (size_t)v * CAP;
  float acc = (l < 9) ? xs[v * 9 + l] : 0.0f;
  int j = 0;
  for (; j + 4 <= c; j += 4) {
    ushort4 u = *(const ushort4*)(cl + j);
    float a0 = (l < 9) ? xs[(int)u.x * 9 + l] : 0.f;
    float a1 = (l < 9) ? xs[(int)u.y * 9 + l] : 0.f;
    float a2 = (l < 9) ? xs[(int)u.z * 9 + l] : 0.f;
    float a3 = (l < 9) ? xs[(int)u.w * 9 + l] : 0.f;
    acc += (a0 + a1) + (a2 + a3);
  }
  for (; j < c; ++j) {
    int u = cl[j];
    if (l < 9) acc += xs[u * 9 + l];
  }
  if (l < 9) sX[g][l] = acc * dinv[v];
  __syncthreads();
  // gemm phase
  int cc = t & 127;
  int g0 = (t >> 7) * 8;
#pragma unroll
  for (int rr = 0; rr < 8; ++rr) {
    int gi = g0 + rr;
    int r = blockIdx.x * 16 + gi;
    float a = sb[cc];
#pragma unroll
    for (int i = 0; i < 9; ++i) a += sX[gi][i] * sW[i * 128 + cc];
    out[(size_t)r * 128 + cc] = (_Float16)(fmaxf(a, 0.0f) * dinv[r]);
  }
}

// ---------- XCD-sliced aggregation, 4-deep (r6 proven best: 58.0 us @F=256) ----------
// F=256 gather pinned ~58 us across 4 structural variants -> fabric floor; lane closed.
__global__ __launch_bounds__(256) void k_aggs(const half4* __restrict__ h,
                                              half4* __restrict__ out,
                                              const int* __restrict__ cnt,
                                              const u16* __restrict__ col,
                                              const float* __restrict__ dinv,
                                              int rowU, int slog) {
  int bid = blockIdx.x;
  int s = bid & ((1 << slog) - 1);
  int chunk = bid >> slog;
  int g = threadIdx.x >> 4;
  int l = threadIdx.x & 15;
  int v = chunk * 16 + g;
  if (v >= NN) return;
  int so = s * 16 + l;                 // half4 offset within row
  int c = cnt[v]; if (c > CAP) c = CAP;
  const u16* cl = col + (size_t)v * CAP;
  half4 sv = h[(size_t)v * rowU + so];
  float ax = (float)sv.x, ay = (float)sv.y, az = (float)sv.z, aw = (float)sv.w;
  int j = 0;
  for (; j + 4 <= c; j += 4) {
    ushort4 u = *(const ushort4*)(cl + j);
    half4 t0 = h[(size_t)u.x * rowU + so];
    half4 t1 = h[(size_t)u.y * rowU + so];
    half4 t2 = h[(size_t)u.z * rowU + so];
    half4 t3 = h[(size_t)u.w * rowU + so];
    ax += ((float)t0.x + (float)t1.x) + ((float)t2.x + (float)t3.x);
    ay += ((float)t0.y + (float)t1.y) + ((float)t2.y + (float)t3.y);
    az += ((float)t0.z + (float)t1.z) + ((float)t2.z + (float)t3.z);
    aw += ((float)t0.w + (float)t1.w) + ((float)t2.w + (float)t3.w);
  }
  for (; j < c; ++j) {
    half4 tv = h[(size_t)cl[j] * rowU + so];
    ax += (float)tv.x; ay += (float)tv.y; az += (float)tv.z; aw += (float)tv.w;
  }
  float d = dinv[v];
  half4 o;
  o.x = (_Float16)(ax * d); o.y = (_Float16)(ay * d);
  o.z = (_Float16)(az * d); o.w = (_Float16)(aw * d);
  out[(size_t)v * rowU + so] = o;
}

// ---------- MFMA fp16 hi/lo-weight GEMM, T14 REGISTER-STAGED PIPELINE ----------
// r12 books: mm = 35-43 us each vs ~13 us floor -> staging latency exposed.
// T14 (container-safe): per K-step, issue global_load(t+1)->regs (normal loads,
// legal in flight across MFMA), MFMA(t) from LDS, barrier (readers done),
// ds_write regs->LDS (single buffer), barrier. The ~600-cy load latency hides
// under the ~1300-cy MFMA phase. Swizzle/decode/epilogue byte-identical to r9.
__global__ __launch_bounds__(256) void k_mm(const _Float16* __restrict__ A,
                                            const _Float16* __restrict__ Bh,
                                            const _Float16* __restrict__ Bl,
                                            const float* __restrict__ bias,
                                            _Float16* __restrict__ C,
                                            const float* __restrict__ dinv,
                                            const int* __restrict__ batch,
                                            unsigned* __restrict__ gpool,
                                            int M, int K, int Nc, int mode) {
  __shared__ __align__(16) _Float16 Alds[128 * 64];   // 16 KB
  __shared__ __align__(16) _Float16 Bhl[128 * 64];    // 16 KB
  __shared__ __align__(16) _Float16 Bll[128 * 64];    // 16 KB
  int bid = blockIdx.x;
  int rblk = (bid >> 4) * 8 + (bid & 7);
  int cblk = (bid >> 3) & 1;
  if (rblk * 128 >= M) return;
  int rowBase = rblk * 128;
  int colBase = cblk * 128;
  int t = threadIdx.x;
  int wave = t >> 6, lane = t & 63;
  int wm = wave & 1, wn = wave >> 1;
  int lm = lane & 15;
  int q  = lane >> 4;

  int srl = wave * 32 + (lane >> 3);
  int sj  = lane & 7;
  int ssw = lane >> 3;
  int gseg = sj ^ ssw;

  // per-lane staging addresses (K-offset added per step)
  size_t gaRow[4], gbRow[4];
  int ldst[4];
#pragma unroll
  for (int c = 0; c < 4; ++c) {
    int rl = srl + c * 8;
    int ga = rowBase + rl; if (ga > M - 1) ga = M - 1;
    gaRow[c] = (size_t)ga * K + gseg * 8;
    gbRow[c] = (size_t)(colBase + rl) * K + gseg * 8;
    ldst[c] = (wave * 32 + c * 8) * 64 + lane * 8;
  }

  f32x4 acc[4][4];
#pragma unroll
  for (int i = 0; i < 4; ++i)
#pragma unroll
    for (int j = 0; j < 4; ++j) acc[i][j] = (f32x4){0.f, 0.f, 0.f, 0.f};

  int nit = K >> 6;
  f16x8 ra[4], rh[4], rb[4];
  // prologue: load + write tile 0
#pragma unroll
  for (int c = 0; c < 4; ++c) {
    ra[c] = *(const f16x8*)(A  + gaRow[c]);
    rh[c] = *(const f16x8*)(Bh + gbRow[c]);
    rb[c] = *(const f16x8*)(Bl + gbRow[c]);
  }
#pragma unroll
  for (int c = 0; c < 4; ++c) {
    *(f16x8*)(Alds + ldst[c]) = ra[c];
    *(f16x8*)(Bhl  + ldst[c]) = rh[c];
    *(f16x8*)(Bll  + ldst[c]) = rb[c];
  }
  __syncthreads();

  for (int it = 0; it < nit; ++it) {
    // issue next tile's loads -> in flight under this step's MFMA
    if (it + 1 < nit) {
      size_t off = (size_t)(it + 1) * 64;
#pragma unroll
      for (int c = 0; c < 4; ++c) {
        ra[c] = *(const f16x8*)(A  + gaRow[c] + off);
        rh[c] = *(const f16x8*)(Bh + gbRow[c] + off);
        rb[c] = *(const f16x8*)(Bl + gbRow[c] + off);
      }
    }

#pragma unroll
    for (int s2 = 0; s2 < 2; ++s2) {
      int slotq = ((s2 << 2) | q);
      int slot = slotq ^ (lm & 7);
      f16x8 vbh[4], vbl[4];
#pragma unroll
      for (int ni = 0; ni < 4; ++ni) {
        int rB = wn * 64 + ni * 16 + lm;
        vbh[ni] = *(const f16x8*)(Bhl + rB * 64 + slot * 8);
        vbl[ni] = *(const f16x8*)(Bll + rB * 64 + slot * 8);
      }
#pragma unroll
      for (int mi = 0; mi < 4; ++mi) {
        int rA = wm * 64 + mi * 16 + lm;
        f16x8 va = *(const f16x8*)(Alds + rA * 64 + slot * 8);
#pragma unroll
        for (int ni = 0; ni < 4; ++ni) {
          acc[mi][ni] = __builtin_amdgcn_mfma_f32_16x16x32_f16(va, vbh[ni], acc[mi][ni], 0, 0, 0);
          acc[mi][ni] = __builtin_amdgcn_mfma_f32_16x16x32_f16(va, vbl[ni], acc[mi][ni], 0, 0, 0);
        }
      }
    }
    __syncthreads();                 // all waves done reading this tile
    if (it + 1 < nit) {              // uniform condition
#pragma unroll
      for (int c = 0; c < 4; ++c) {
        *(f16x8*)(Alds + ldst[c]) = ra[c];
        *(f16x8*)(Bhl  + ldst[c]) = rh[c];
        *(f16x8*)(Bll  + ldst[c]) = rb[c];
      }
      __syncthreads();               // writes visible before next MFMA
    }
  }

  int rowOff = (lane >> 4) * 4;
  if (mode == 2) {
    __syncthreads();
    unsigned* ldsPool = (unsigned*)Alds;
    for (int i = t; i < 4 * 256; i += 256) ldsPool[i] = 0u;
    __syncthreads();
    int b0 = batch[rowBase];
#pragma unroll
    for (int mi = 0; mi < 4; ++mi) {
#pragma unroll
      for (int ni = 0; ni < 4; ++ni) {
        int gc = colBase + wn * 64 + ni * 16 + lm;
        float bsv = bias[gc];
#pragma unroll
        for (int r = 0; r < 4; ++r) {
          int gr = rowBase + wm * 64 + mi * 16 + rowOff + r;
          if (gr < M) {
            float v = acc[mi][ni][r] + bsv;
            int idx = batch[gr] - b0;
            if (idx < 0) idx = 0;
            if (idx > 3) idx = 3;
            atomicMax(&ldsPool[idx * 256 + gc], f2mono(v));
          }
        }
      }
    }
    __syncthreads();
#pragma unroll
    for (int s4 = 0; s4 < 4; ++s4) {
      unsigned mv = ldsPool[s4 * 256 + t];
      int gb = b0 + s4;
      if (mv && gb < NG) atomicMax(&gpool[gb * 256 + t], mv);
    }
  } else {
#pragma unroll
    for (int mi = 0; mi < 4; ++mi) {
#pragma unroll
      for (int ni = 0; ni < 4; ++ni) {
        int gc = colBase + wn * 64 + ni * 16 + lm;
        float bsv = bias[gc];
#pragma unroll
        for (int r = 0; r < 4; ++r) {
          int gr = rowBase + wm * 64 + mi * 16 + rowOff + r;
          if (gr < M) {
            float v = fmaxf(acc[mi][ni][r] + bsv, 0.0f);
            C[(size_t)gr * Nc + gc] = (_Float16)(v * dinv[gr]);
          }
        }
      }
    }
  }
}

// ---------- dense head ----------
__global__ __launch_bounds__(256) void k_head(const unsigned* __restrict__ g,
                                              const float* __restrict__ Wl2, const float* __restrict__ bl2,
                                              const float* __restrict__ Wl3, const float* __restrict__ bl3,
                                              const float* __restrict__ Wl, const float* __restrict__ bl,
                                              float* __restrict__ out) {
  __shared__ float s0[256];
  __shared__ float s1[128];
  __shared__ float s2[128];
  int b = blockIdx.x, t = threadIdx.x;
  s0[t] = mono2f(g[b * 256 + t]);
  __syncthreads();
  if (t < 128) {
    float acc = bl2[t];
    for (int k = 0; k < 256; ++k) acc += s0[k] * Wl2[k * 128 + t];
    s1[t] = fmaxf(acc, 0.0f);
  }
  __syncthreads();
  if (t < 128) {
    float acc = bl3[t];
    for (int k = 0; k < 128; ++k) acc += s1[k] * Wl3[k * 128 + t];
    s2[t] = fmaxf(acc, 0.0f);
  }
  __syncthreads();
  if (t < 10) {
    float acc = bl[t];
    for (int k = 0; k < 128; ++k) acc += s2[k] * Wl[k * 10 + t];
    out[b * 10 + t] = acc;
  }
}

extern "C" void kernel_launch(void* const* d_in, const int* in_sizes, int n_in,
                              void* d_out, int out_size, void* d_ws, size_t ws_size,
                              hipStream_t stream) {
  const float* x   = (const float*)d_in[0];
  const int* eidx  = (const int*)d_in[1];
  const int* batch = (const int*)d_in[2];
  const float* W1 = (const float*)d_in[3];   const float* b1 = (const float*)d_in[4];
  const float* W2 = (const float*)d_in[5];   const float* b2 = (const float*)d_in[6];
  const float* W3 = (const float*)d_in[7];   const float* b3 = (const float*)d_in[8];
  const float* W4 = (const float*)d_in[9];   const float* b4 = (const float*)d_in[10];
  const float* Wl2 = (const float*)d_in[11]; const float* bl2 = (const float*)d_in[12];
  const float* Wl3 = (const float*)d_in[13]; const float* bl3 = (const float*)d_in[14];
  const float* Wl  = (const float*)d_in[15]; const float* bl  = (const float*)d_in[16];
  float* out = (float*)d_out;

  // ---- workspace carve ----
  _Float16* bufA = (_Float16*)d_ws;                                // NN*256 fp16
  _Float16* bufB = bufA + (size_t)NN * 256;                        // NN*256 fp16
  int* cnt  = (int*)(bufB + (size_t)NN * 256);                     // NN
  float* dinv = (float*)(cnt + NN);                                // NN
  u16* col  = (u16*)(dinv + NN);                                   // NN*CAP ushort
  unsigned* g = (unsigned*)(col + (size_t)NN * CAP);               // NG*256
  _Float16* W2h = (_Float16*)(g + NG * 256);                       // 256*128
  _Float16* W2l = W2h + 256 * 128;
  _Float16* W3h = W2l + 256 * 128;                                 // 256*256
  _Float16* W3l = W3h + 256 * 256;
  _Float16* W4h = W3l + 256 * 256;
  _Float16* W4l = W4h + 256 * 256;
  float* xs = (float*)bufB;        // NN*9 fp32 in bufB: dead before layer-2 aggs writes bufB

  const int* src = eidx;
  const int* dst = eidx + NE;

  hipMemsetAsync(cnt, 0, NN * sizeof(int), stream);

  const int cntGrid = 8 * ((NE + 256 * EPT - 1) / (256 * EPT));
  k_count<<<cntGrid, 256, 0, stream>>>(src, dst, cnt, col);
  k_dinv<<<(NN + 255) / 256, 256, 0, stream>>>(cnt, dinv, x, xs, g);

  k_splitw3<<<(128 * 256 + 2 * 256 * 256 + 255) / 256, 256, 0, stream>>>(
      W2, W3, W4, W2h, W2l, W3h, W3l, W4h, W4l);

  const int nchunk = (NN + 15) / 16;           // 3125: 16 nodes per block, exact
  const int mmGrid = 784;                      // 392 row-blocks x 2 col-blocks, XCD-paired

  // layer 1: FUSED agg9 + GEMM 9->128 (+relu, *dinv) xs(bufB) -> bufA fp16
  k_l1<<<nchunk, 256, 0, stream>>>(xs, W1, b1, dinv, cnt, col, bufA);

  // layer 2: sliced gather 128-dim bufA->bufB (2 slices), MFMA GEMM 128->256 bufB->bufA
  k_aggs<<<nchunk * 2, 256, 0, stream>>>((const half4*)bufA, (half4*)bufB, cnt, col, dinv, 32, 1);
  k_mm<<<mmGrid, 256, 0, stream>>>(bufB, W2h, W2l, b2, bufA, dinv, batch, g, NN, 128, 256, 1);

  // layer 3: sliced gather 256-dim bufA->bufB (4 slices), GEMM bufB->bufA
  k_aggs<<<nchunk * 4, 256, 0, stream>>>((const half4*)bufA, (half4*)bufB, cnt, col, dinv, 64, 2);
  k_mm<<<mmGrid, 256, 0, stream>>>(bufB, W3h, W3l, b3, bufA, dinv, batch, g, NN, 256, 256, 1);

  // layer 4: sliced gather 256-dim bufA->bufB, GEMM + fused max-pool (no C write)
  k_aggs<<<nchunk * 4, 256, 0, stream>>>((const half4*)bufA, (half4*)bufB, cnt, col, dinv, 64, 2);
  k_mm<<<mmGrid, 256, 0, stream>>>(bufB, W4h, W4l, b4, bufA, dinv, batch, g, NN, 256, 256, 2);

  // head
  k_head<<<NG, 256, 0, stream>>>(g, Wl2, bl2, Wl3, bl3, Wl, bl, out);
}

// Round 15
// 386.942 us; speedup vs baseline: 1.0779x; 1.0713x over previous
//
#include <hip/hip_runtime.h>
#include <float.h>

#define NN 50000
#define NE 800000
#define NG 64
#define CAP 64

typedef __attribute__((ext_vector_type(8))) _Float16 f16x8;
typedef __attribute__((ext_vector_type(4))) float f32x4;
typedef __attribute__((ext_vector_type(4))) _Float16 half4;
typedef __attribute__((ext_vector_type(8))) unsigned short u16x8;
typedef unsigned int u32;
typedef unsigned short u16;
typedef unsigned long long u64;

// ---------- helpers ----------
__device__ __forceinline__ unsigned f2mono(float f) {
  unsigned b = __float_as_uint(f);
  return (b & 0x80000000u) ? ~b : (b | 0x80000000u);
}
__device__ __forceinline__ float mono2f(unsigned u) {
  unsigned b = (u & 0x80000000u) ? (u & 0x7fffffffu) : ~u;
  return __uint_as_float(b);
}
// async global->LDS 16B DMA (gfx950). LDS dest must be wave-uniform base + lane*16.
// NOTE (r2/r3/r11): DMAs left in flight ACROSS an MFMA phase wedged the container
// 3/3 times on this harness. Only issue->drain->use.
__device__ __forceinline__ void gl_lds16(const void* g, void* l) {
  __builtin_amdgcn_global_load_lds((const __attribute__((address_space(1))) u32*)g,
                                   (__attribute__((address_space(3))) u32*)l, 16, 0, 0);
}

// ---------- degree count + ELL fill, XCD-partitioned, int4 dst loads ----------
// bid&7 = slice s -> XCD s under %8 round-robin; slice commits only (dst&7)==s
// edges (r6: write amp 44->~10MB). r13: latency-bound (VALUBusy 6.6%) -> load dst
// as int4 (4x fewer loads, all 4 issued up-front for MLP). 4096 edges/block.
__global__ __launch_bounds__(256) void k_count(const int* __restrict__ src,
                                               const int* __restrict__ dst,
                                               int* __restrict__ cnt,
                                               u16* __restrict__ col) {
  int s = blockIdx.x & 7;
  int base = (blockIdx.x >> 3) * 4096;
  const int4* dst4 = (const int4*)dst;
  int4 q[4];
  int ei[4];
  bool ok[4];
#pragma unroll
  for (int r = 0; r < 4; ++r) {
    ei[r] = base + (r * 256 + (int)threadIdx.x) * 4;
    ok[r] = ei[r] < NE;                      // NE % 4 == 0: int4 never straddles
    if (ok[r]) q[r] = dst4[ei[r] >> 2];
  }
#pragma unroll
  for (int r = 0; r < 4; ++r) {
    if (!ok[r]) continue;
    int dd0 = q[r].x, dd1 = q[r].y, dd2 = q[r].z, dd3 = q[r].w;
#pragma unroll
    for (int k = 0; k < 4; ++k) {
      int d = (k == 0) ? dd0 : (k == 1) ? dd1 : (k == 2) ? dd2 : dd3;
      if ((d & 7) != s) continue;
      if ((unsigned)d >= NN) continue;
      int sv = src[ei[r] + k];
      if ((unsigned)sv >= NN) continue;
      int pos = atomicAdd(&cnt[d], 1);
      if (pos < CAP) col[d * CAP + pos] = (u16)sv;
    }
  }
}

// dinv + pre-scaled input xs = x*dinv; zero pool buffer; PAD col tails with the
// NN sentinel (points at the zero row) and zero bufA's two pad rows.
// r14 BUG FIX: a u64 holds 4 fp16 -> the 128-fp16 pad row needs 32 u64 (not 16)
// and the 256-fp16 pad row needs 64 u64 (not 32). Half-zeroed rows injected
// workspace garbage into sentinel gathers (absmax 4.6e-2 fail).
__global__ void k_dinv(const int* __restrict__ cnt, float* __restrict__ dinv,
                       const float* __restrict__ x, float* __restrict__ xs,
                       unsigned* __restrict__ g, u16* __restrict__ col,
                       _Float16* __restrict__ bufA) {
  int v = blockIdx.x * blockDim.x + threadIdx.x;
  if (v >= NN) return;
  if (v < NG * 256) g[v] = 0u;
  if (v < 32) ((u64*)(bufA + (size_t)NN * 128))[v] = 0ULL;   // 128 fp16 pad row (F=128)
  if (v < 64) ((u64*)(bufA + (size_t)NN * 256))[v] = 0ULL;   // 256 fp16 pad row (F=256)
  int cc = cnt[v];
  float d = rsqrtf((float)cc + 1.0f);
  dinv[v] = d;
#pragma unroll
  for (int i = 0; i < 9; ++i) xs[v * 9 + i] = x[v * 9 + i] * d;
  int c = cc > CAP ? CAP : cc;
  u16* cr = col + (size_t)v * CAP;
  for (int i = c; i < CAP; ++i) cr[i] = (u16)NN;             // sentinel -> zero row
}

// ---------- fused weight split+transpose for W2,W3,W4: W[K][Nc] -> Wh/Wl[Nc][K] ----------
__device__ __forceinline__ void splitw1(const float* W, _Float16* Wh, _Float16* Wl,
                                        int i, int K, int Nc) {
  int k = i / Nc, n = i - k * Nc;
  float w = W[i];
  _Float16 h = (_Float16)w;
  _Float16 l = (_Float16)(w - (float)h);
  Wh[(size_t)n * K + k] = h;
  Wl[(size_t)n * K + k] = l;
}
__global__ void k_splitw3(const float* __restrict__ W2, const float* __restrict__ W3,
                          const float* __restrict__ W4,
                          _Float16* __restrict__ W2h, _Float16* __restrict__ W2l,
                          _Float16* __restrict__ W3h, _Float16* __restrict__ W3l,
                          _Float16* __restrict__ W4h, _Float16* __restrict__ W4l) {
  int i = blockIdx.x * 256 + threadIdx.x;
  const int n2 = 128 * 256, n3 = 256 * 256;
  if (i < n2) splitw1(W2, W2h, W2l, i, 128, 256);
  else if (i < n2 + n3) splitw1(W3, W3h, W3l, i - n2, 256, 256);
  else if (i < n2 + 2 * n3) splitw1(W4, W4h, W4l, i - n2 - n3, 256, 256);
}

// ---------- FUSED layer 1: agg9 gather + GEMM 9->128 (+bias, relu, *dinv) ----------
// 3125 blocks x 256 thr; 16 nodes/block (50000 = 16*3125 exactly -> uniform barriers).
__global__ __launch_bounds__(256) void k_l1(const float* __restrict__ xs,
                                            const float* __restrict__ W,
                                            const float* __restrict__ bias,
                                            const float* __restrict__ dinv,
                                            const int* __restrict__ cnt,
                                            const u16* __restrict__ col,
                                            _Float16* __restrict__ out) {
  __shared__ float sW[9 * 128];
  __shared__ float sb[128];
  __shared__ float sX[16][12];      // 9 used, padded
  int t = threadIdx.x;
  if (t < 128) sb[t] = bias[t];
  for (int i = t; i < 9 * 128; i += 256) sW[i] = W[i];
  // gather phase
  int g = t >> 4, l = t & 15;
  int v = blockIdx.x * 16 + g;      // always < NN (exact tiling)
  int c = cnt[v]; if (c > CAP) c = CAP;
  const u16* cl = col + (size_t)v * CAP;
  float acc = (l < 9) ? xs[v * 9 + l] : 0.0f;
  int j = 0;
  for (; j + 4 <= c; j += 4) {
    ushort4 u = *(const ushort4*)(cl + j);
    float a0 = (l < 9) ? xs[(int)u.x * 9 + l] : 0.f;
    float a1 = (l < 9) ? xs[(int)u.y * 9 + l] : 0.f;
    float a2 = (l < 9) ? xs[(int)u.z * 9 + l] : 0.f;
    float a3 = (l < 9) ? xs[(int)u.w * 9 + l] : 0.f;
    acc += (a0 + a1) + (a2 + a3);
  }
  for (; j < c; ++j) {
    int u = cl[j];
    if (l < 9) acc += xs[u * 9 + l];
  }
  if (l < 9) sX[g][l] = acc * dinv[v];
  __syncthreads();
  // gemm phase
  int cc = t & 127;
  int g0 = (t >> 7) * 8;
#pragma unroll
  for (int rr = 0; rr < 8; ++rr) {
    int gi = g0 + rr;
    int r = blockIdx.x * 16 + gi;
    float a = sb[cc];
#pragma unroll
    for (int i = 0; i < 9; ++i) a += sX[gi][i] * sW[i * 128 + cc];
    out[(size_t)r * 128 + cc] = (_Float16)(fmaxf(a, 0.0f) * dinv[r]);
  }
}

// ---------- XCD-sliced aggregation, 8-deep UNCONDITIONAL (sentinel-padded ELL) ----------
// r8's 16-deep failed because clamps serialized the loads (VGPR=32 tell). With the
// col tail padded to the NN zero-row sentinel, all 8 gathers + adds are branch-free:
// loads issue back-to-back -> 2x batch MLP vs the 4-deep form.
__global__ __launch_bounds__(256) void k_aggs(const half4* __restrict__ h,
                                              half4* __restrict__ out,
                                              const int* __restrict__ cnt,
                                              const u16* __restrict__ col,
                                              const float* __restrict__ dinv,
                                              int rowU, int slog) {
  int bid = blockIdx.x;
  int s = bid & ((1 << slog) - 1);
  int chunk = bid >> slog;
  int g = threadIdx.x >> 4;
  int l = threadIdx.x & 15;
  int v = chunk * 16 + g;
  if (v >= NN) return;
  int so = s * 16 + l;                 // half4 offset within row
  int c = cnt[v]; if (c > CAP) c = CAP;
  const u16* cl = col + (size_t)v * CAP;
  const half4* hb = h + so;
  half4 sv = hb[(size_t)v * rowU];
  float ax = (float)sv.x, ay = (float)sv.y, az = (float)sv.z, aw = (float)sv.w;
  for (int j = 0; j < c; j += 8) {
    u16x8 u = *(const u16x8*)(cl + j);
    half4 t0 = hb[(size_t)u[0] * rowU];
    half4 t1 = hb[(size_t)u[1] * rowU];
    half4 t2 = hb[(size_t)u[2] * rowU];
    half4 t3 = hb[(size_t)u[3] * rowU];
    half4 t4 = hb[(size_t)u[4] * rowU];
    half4 t5 = hb[(size_t)u[5] * rowU];
    half4 t6 = hb[(size_t)u[6] * rowU];
    half4 t7 = hb[(size_t)u[7] * rowU];
    ax += (((float)t0.x + (float)t1.x) + ((float)t2.x + (float)t3.x)) +
          (((float)t4.x + (float)t5.x) + ((float)t6.x + (float)t7.x));
    ay += (((float)t0.y + (float)t1.y) + ((float)t2.y + (float)t3.y)) +
          (((float)t4.y + (float)t5.y) + ((float)t6.y + (float)t7.y));
    az += (((float)t0.z + (float)t1.z) + ((float)t2.z + (float)t3.z)) +
          (((float)t4.z + (float)t5.z) + ((float)t6.z + (float)t7.z));
    aw += (((float)t0.w + (float)t1.w) + ((float)t2.w + (float)t3.w)) +
          (((float)t4.w + (float)t5.w) + ((float)t6.w + (float)t7.w));
  }
  float d = dinv[v];
  half4 o;
  o.x = (_Float16)(ax * d); o.y = (_Float16)(ay * d);
  o.z = (_Float16)(az * d); o.w = (_Float16)(aw * d);
  out[(size_t)v * rowU + so] = o;
}

// ---------- MFMA fp16 hi/lo-weight GEMM, DMA LDS staging (r9 proven form, 404.3us) ----------
// mm lane CLOSED (r4/r10/r11/r13: B-direct +54, timeshare +9, DMA-pipe wedge,
// reg-staged +10). This 2-barrier 48KB shape is the local optimum on this harness.
__global__ __launch_bounds__(256) void k_mm(const _Float16* __restrict__ A,
                                            const _Float16* __restrict__ Bh,
                                            const _Float16* __restrict__ Bl,
                                            const float* __restrict__ bias,
                                            _Float16* __restrict__ C,
                                            const float* __restrict__ dinv,
                                            const int* __restrict__ batch,
                                            unsigned* __restrict__ gpool,
                                            int M, int K, int Nc, int mode) {
  __shared__ __align__(16) _Float16 Alds[128 * 64];   // 16 KB
  __shared__ __align__(16) _Float16 Bhl[128 * 64];    // 16 KB
  __shared__ __align__(16) _Float16 Bll[128 * 64];    // 16 KB
  int bid = blockIdx.x;
  int rblk = (bid >> 4) * 8 + (bid & 7);
  int cblk = (bid >> 3) & 1;
  if (rblk * 128 >= M) return;
  int rowBase = rblk * 128;
  int colBase = cblk * 128;
  int t = threadIdx.x;
  int wave = t >> 6, lane = t & 63;
  int wm = wave & 1, wn = wave >> 1;
  int lm = lane & 15;
  int q  = lane >> 4;

  int srl = wave * 32 + (lane >> 3);
  int sj  = lane & 7;
  int ssw = lane >> 3;
  int gseg = sj ^ ssw;

  f32x4 acc[4][4];
#pragma unroll
  for (int i = 0; i < 4; ++i)
#pragma unroll
    for (int j = 0; j < 4; ++j) acc[i][j] = (f32x4){0.f, 0.f, 0.f, 0.f};

  int nit = K >> 6;
  for (int it = 0; it < nit; ++it) {
    __syncthreads();
#pragma unroll
    for (int c = 0; c < 4; ++c) {
      int rl = srl + c * 8;
      int ga = rowBase + rl; if (ga > M - 1) ga = M - 1;
      int gb = colBase + rl;
      unsigned off = (unsigned)it * 64 + gseg * 8;
      int ldst = (wave * 32 + c * 8) * 64 + lane * 8;
      gl_lds16(A  + (size_t)ga * K + off, Alds + ldst);
      gl_lds16(Bh + (size_t)gb * K + off, Bhl + ldst);
      gl_lds16(Bl + (size_t)gb * K + off, Bll + ldst);
    }
    __syncthreads();

#pragma unroll
    for (int s2 = 0; s2 < 2; ++s2) {
      int slotq = ((s2 << 2) | q);
      f16x8 vbh[4], vbl[4];
#pragma unroll
      for (int ni = 0; ni < 4; ++ni) {
        int rB = wn * 64 + ni * 16 + lm;
        int slot = slotq ^ (lm & 7);
        vbh[ni] = *(const f16x8*)(Bhl + rB * 64 + slot * 8);
        vbl[ni] = *(const f16x8*)(Bll + rB * 64 + slot * 8);
      }
#pragma unroll
      for (int mi = 0; mi < 4; ++mi) {
        int rA = wm * 64 + mi * 16 + lm;
        int slot = slotq ^ (lm & 7);
        f16x8 va = *(const f16x8*)(Alds + rA * 64 + slot * 8);
#pragma unroll
        for (int ni = 0; ni < 4; ++ni) {
          acc[mi][ni] = __builtin_amdgcn_mfma_f32_16x16x32_f16(va, vbh[ni], acc[mi][ni], 0, 0, 0);
          acc[mi][ni] = __builtin_amdgcn_mfma_f32_16x16x32_f16(va, vbl[ni], acc[mi][ni], 0, 0, 0);
        }
      }
    }
  }

  int rowOff = (lane >> 4) * 4;
  if (mode == 2) {
    __syncthreads();
    unsigned* ldsPool = (unsigned*)Alds;
    for (int i = t; i < 4 * 256; i += 256) ldsPool[i] = 0u;
    __syncthreads();
    int b0 = batch[rowBase];
#pragma unroll
    for (int mi = 0; mi < 4; ++mi) {
#pragma unroll
      for (int ni = 0; ni < 4; ++ni) {
        int gc = colBase + wn * 64 + ni * 16 + lm;
        float bsv = bias[gc];
#pragma unroll
        for (int r = 0; r < 4; ++r) {
          int gr = rowBase + wm * 64 + mi * 16 + rowOff + r;
          if (gr < M) {
            float v = acc[mi][ni][r] + bsv;
            int idx = batch[gr] - b0;
            if (idx < 0) idx = 0;
            if (idx > 3) idx = 3;
            atomicMax(&ldsPool[idx * 256 + gc], f2mono(v));
          }
        }
      }
    }
    __syncthreads();
#pragma unroll
    for (int s4 = 0; s4 < 4; ++s4) {
      unsigned mv = ldsPool[s4 * 256 + t];
      int gb = b0 + s4;
      if (mv && gb < NG) atomicMax(&gpool[gb * 256 + t], mv);
    }
  } else {
#pragma unroll
    for (int mi = 0; mi < 4; ++mi) {
#pragma unroll
      for (int ni = 0; ni < 4; ++ni) {
        int gc = colBase + wn * 64 + ni * 16 + lm;
        float bsv = bias[gc];
#pragma unroll
        for (int r = 0; r < 4; ++r) {
          int gr = rowBase + wm * 64 + mi * 16 + rowOff + r;
          if (gr < M) {
            float v = fmaxf(acc[mi][ni][r] + bsv, 0.0f);
            C[(size_t)gr * Nc + gc] = (_Float16)(v * dinv[gr]);
          }
        }
      }
    }
  }
}

// ---------- dense head ----------
__global__ __launch_bounds__(256) void k_head(const unsigned* __restrict__ g,
                                              const float* __restrict__ Wl2, const float* __restrict__ bl2,
                                              const float* __restrict__ Wl3, const float* __restrict__ bl3,
                                              const float* __restrict__ Wl, const float* __restrict__ bl,
                                              float* __restrict__ out) {
  __shared__ float s0[256];
  __shared__ float s1[128];
  __shared__ float s2[128];
  int b = blockIdx.x, t = threadIdx.x;
  s0[t] = mono2f(g[b * 256 + t]);
  __syncthreads();
  if (t < 128) {
    float acc = bl2[t];
    for (int k = 0; k < 256; ++k) acc += s0[k] * Wl2[k * 128 + t];
    s1[t] = fmaxf(acc, 0.0f);
  }
  __syncthreads();
  if (t < 128) {
    float acc = bl3[t];
    for (int k = 0; k < 128; ++k) acc += s1[k] * Wl3[k * 128 + t];
    s2[t] = fmaxf(acc, 0.0f);
  }
  __syncthreads();
  if (t < 10) {
    float acc = bl[t];
    for (int k = 0; k < 128; ++k) acc += s2[k] * Wl[k * 10 + t];
    out[b * 10 + t] = acc;
  }
}

extern "C" void kernel_launch(void* const* d_in, const int* in_sizes, int n_in,
                              void* d_out, int out_size, void* d_ws, size_t ws_size,
                              hipStream_t stream) {
  const float* x   = (const float*)d_in[0];
  const int* eidx  = (const int*)d_in[1];
  const int* batch = (const int*)d_in[2];
  const float* W1 = (const float*)d_in[3];   const float* b1 = (const float*)d_in[4];
  const float* W2 = (const float*)d_in[5];   const float* b2 = (const float*)d_in[6];
  const float* W3 = (const float*)d_in[7];   const float* b3 = (const float*)d_in[8];
  const float* W4 = (const float*)d_in[9];   const float* b4 = (const float*)d_in[10];
  const float* Wl2 = (const float*)d_in[11]; const float* bl2 = (const float*)d_in[12];
  const float* Wl3 = (const float*)d_in[13]; const float* bl3 = (const float*)d_in[14];
  const float* Wl  = (const float*)d_in[15]; const float* bl  = (const float*)d_in[16];
  float* out = (float*)d_out;

  // ---- workspace carve: buffers have NN+1 rows (row NN = zero pad row) ----
  _Float16* bufA = (_Float16*)d_ws;                                // (NN+1)*256 fp16
  _Float16* bufB = bufA + (size_t)(NN + 1) * 256;                  // (NN+1)*256 fp16
  int* cnt  = (int*)(bufB + (size_t)(NN + 1) * 256);               // NN
  float* dinv = (float*)(cnt + NN);                                // NN
  u16* col  = (u16*)(dinv + NN);                                   // NN*CAP ushort
  unsigned* g = (unsigned*)(col + (size_t)NN * CAP);               // NG*256
  _Float16* W2h = (_Float16*)(g + NG * 256);                       // 256*128
  _Float16* W2l = W2h + 256 * 128;
  _Float16* W3h = W2l + 256 * 128;                                 // 256*256
  _Float16* W3l = W3h + 256 * 256;
  _Float16* W4h = W3l + 256 * 256;
  _Float16* W4l = W4h + 256 * 256;
  float* xs = (float*)bufB;        // NN*9 fp32 in bufB head: dead before aggs L2 writes bufB

  const int* src = eidx;
  const int* dst = eidx + NE;

  hipMemsetAsync(cnt, 0, NN * sizeof(int), stream);

  const int cntGrid = 8 * ((NE + 4095) / 4096);
  k_count<<<cntGrid, 256, 0, stream>>>(src, dst, cnt, col);
  k_dinv<<<(NN + 255) / 256, 256, 0, stream>>>(cnt, dinv, x, xs, g, col, bufA);

  k_splitw3<<<(128 * 256 + 2 * 256 * 256 + 255) / 256, 256, 0, stream>>>(
      W2, W3, W4, W2h, W2l, W3h, W3l, W4h, W4l);

  const int nchunk = (NN + 15) / 16;           // 3125: 16 nodes per block, exact
  const int mmGrid = 784;                      // 392 row-blocks x 2 col-blocks, XCD-paired

  // layer 1: FUSED agg9 + GEMM 9->128 (+relu, *dinv) xs(bufB) -> bufA fp16
  k_l1<<<nchunk, 256, 0, stream>>>(xs, W1, b1, dinv, cnt, col, bufA);

  // layer 2: sliced gather 128-dim bufA->bufB (2 slices), MFMA GEMM 128->256 bufB->bufA
  k_aggs<<<nchunk * 2, 256, 0, stream>>>((const half4*)bufA, (half4*)bufB, cnt, col, dinv, 32, 1);
  k_mm<<<mmGrid, 256, 0, stream>>>(bufB, W2h, W2l, b2, bufA, dinv, batch, g, NN, 128, 256, 1);

  // layer 3: sliced gather 256-dim bufA->bufB (4 slices), GEMM bufB->bufA
  k_aggs<<<nchunk * 4, 256, 0, stream>>>((const half4*)bufA, (half4*)bufB, cnt, col, dinv, 64, 2);
  k_mm<<<mmGrid, 256, 0, stream>>>(bufB, W3h, W3l, b3, bufA, dinv, batch, g, NN, 256, 256, 1);

  // layer 4: sliced gather 256-dim bufA->bufB, GEMM + fused max-pool (no C write)
  k_aggs<<<nchunk * 4, 256, 0, stream>>>((const half4*)bufA, (half4*)bufB, cnt, col, dinv, 64, 2);
  k_mm<<<mmGrid, 256, 0, stream>>>(bufB, W4h, W4l, b4, bufA, dinv, batch, g, NN, 256, 256, 2);

  // head
  k_head<<<NG, 256, 0, stream>>>(g, Wl2, bl2, Wl3, bl3, Wl, bl, out);
}